// Round 17
// baseline (421.507 us; speedup 1.0000x reference)
//
#include <hip/hip_runtime.h>

typedef __attribute__((ext_vector_type(8))) short bf16x8;
typedef __attribute__((ext_vector_type(4))) float f32x4;
typedef unsigned short ushort_t;

// ---------------------------------------------------------------------------
// fp32 -> bf16 RNE helpers
// ---------------------------------------------------------------------------
__device__ inline unsigned f2bf_rnd(float f) {
    unsigned u = __float_as_uint(f);
    return u + 0x7FFFu + ((u >> 16) & 1u);   // high 16 bits = RNE bf16
}

__device__ inline void split8(f32x4 a, f32x4 b, bf16x8& hv, bf16x8& lv) {
    float f[8] = {a.x, a.y, a.z, a.w, b.x, b.y, b.z, b.w};
    unsigned r[8], l[8];
#pragma unroll
    for (int j = 0; j < 8; ++j) r[j] = f2bf_rnd(f[j]);
#pragma unroll
    for (int j = 0; j < 8; ++j) {
        float hf = __uint_as_float(r[j] & 0xFFFF0000u);
        l[j] = f2bf_rnd(f[j] - hf);
    }
    union { unsigned u[4]; bf16x8 v; } H, L;
#pragma unroll
    for (int p = 0; p < 4; ++p) {
        H.u[p] = __builtin_amdgcn_perm(r[2 * p + 1], r[2 * p], 0x07060302u);
        L.u[p] = __builtin_amdgcn_perm(l[2 * p + 1], l[2 * p], 0x07060302u);
    }
    hv = H.v; lv = L.v;
}

// direct HBM->LDS DMA, 16B per lane; LDS dest = wave-uniform base + lane*16
__device__ inline void gload_lds16(const void* g, void* l) {
    __builtin_amdgcn_global_load_lds(
        (const __attribute__((address_space(1))) void*)g,
        (__attribute__((address_space(3))) void*)l, 16, 0, 0);
}

// ---------------------------------------------------------------------------
// Kernel 1: pack W_in [64][1024] fp32 -> Wp bf16 hi/lo in MFMA-fragment layout
// Wp layout: [chunk 32][hl 2][kg 4][n 64][j 8]  (ushort), 256 KB total
// (byte-identical to R12..R16)
// ---------------------------------------------------------------------------
__global__ void pack_w_kernel(const float* __restrict__ Win, ushort_t* __restrict__ Wp) {
    int idx = blockIdx.x * 256 + threadIdx.x;   // 0..65535
    int j  = idx & 7;
    int n  = (idx >> 3) & 63;
    int kg = (idx >> 9) & 3;
    int ch = idx >> 11;                          // 0..31
    int k  = ch * 32 + kg * 8 + j;
    float v = Win[n * 1024 + k];
    unsigned hb = f2bf_rnd(v) >> 16;
    float hf = __uint_as_float(hb << 16);
    unsigned lb = f2bf_rnd(v - hf) >> 16;
    Wp[((ch * 2 + 0) * 4 + kg) * 512 + n * 8 + j] = (ushort_t)hb;
    Wp[((ch * 2 + 1) * 4 + kg) * 512 + n * 8 + j] = (ushort_t)lb;
}

// ---------------------------------------------------------------------------
// Kernel 2 (v4b, byte-identical to R14's measured 131us GEMM): global_load_lds
// pipeline, counted vmcnt, two barriers/tile, compiler-interleaved ds_reads.
// ---------------------------------------------------------------------------
__global__ __launch_bounds__(256) void gemm_ext_kernel(const float* __restrict__ x,
                                                       const ushort_t* __restrict__ Wp,
                                                       const float* __restrict__ bin,
                                                       float* __restrict__ ext) {
    __shared__ __align__(16) float    Asm[2][4096];   // 2 x 16 KB, [row][col64]
    __shared__ __align__(16) ushort_t Bsm[2][8192];   // 2 x 16 KB, linear

    const int tid  = threadIdx.x;        // 0..255
    const int lane = tid & 63;
    const int wave = tid >> 6;
    const int l15  = lane & 15;
    const int lg   = lane >> 4;

    const long rowbase = (long)blockIdx.x * 64;

    auto issue_tile = [&](int kt, int buf) {
        const float* xb = x + rowbase * 1024 + kt * 64;
        const ushort_t* wb = Wp + kt * 8192;
#pragma unroll
        for (int i = 0; i < 4; ++i) {
            const int slot = i * 256 + tid;           // = i*256 + wave*64 + lane
            gload_lds16(xb + (long)(slot >> 4) * 1024 + (slot & 15) * 4,
                        &Asm[buf][(i * 256 + wave * 64) * 4]);
        }
#pragma unroll
        for (int i = 0; i < 4; ++i) {
            const int slot = i * 256 + tid;
            gload_lds16(wb + slot * 8,
                        &Bsm[buf][(i * 256 + wave * 64) * 8]);
        }
    };

    f32x4 acc[4];
#pragma unroll
    for (int n = 0; n < 4; ++n) acc[n] = (f32x4){0.f, 0.f, 0.f, 0.f};

    issue_tile(0, 0);
    issue_tile(1, 1);

#pragma unroll 1
    for (int kt = 0; kt < 16; ++kt) {
        const int buf = kt & 1;
        if (kt < 15) {
            asm volatile("s_waitcnt vmcnt(8)" ::: "memory");
        } else {
            asm volatile("s_waitcnt vmcnt(0)" ::: "memory");
        }
        asm volatile("s_barrier" ::: "memory");

#pragma unroll
        for (int kc = 0; kc < 2; ++kc) {
            const float* ap = &Asm[buf][(wave * 16 + l15) * 64 + kc * 32 + lg * 8];
            f32x4 a0 = *(const f32x4*)ap;
            f32x4 a1 = *(const f32x4*)(ap + 4);
            bf16x8 Ahi, Alo;
            split8(a0, a1, Ahi, Alo);
            const ushort_t* bp = &Bsm[buf][kc * 4096 + lg * 512 + l15 * 8];
#pragma unroll
            for (int nq = 0; nq < 4; ++nq) {
                bf16x8 bh = *(const bf16x8*)(bp + nq * 128);
                bf16x8 bl = *(const bf16x8*)(bp + 2048 + nq * 128);
                acc[nq] = __builtin_amdgcn_mfma_f32_16x16x32_bf16(Ahi, bh, acc[nq], 0, 0, 0);
                acc[nq] = __builtin_amdgcn_mfma_f32_16x16x32_bf16(Ahi, bl, acc[nq], 0, 0, 0);
                acc[nq] = __builtin_amdgcn_mfma_f32_16x16x32_bf16(Alo, bh, acc[nq], 0, 0, 0);
            }
        }

        if (kt + 2 < 16) {
            asm volatile("s_barrier" ::: "memory");   // all waves done reading buf
            issue_tile(kt + 2, buf);
        }
    }

    // epilogue: add bias, store.  C/D map: col = lane&15, row = (lane>>4)*4 + r
#pragma unroll
    for (int nq = 0; nq < 4; ++nq) {
        float bias = bin[nq * 16 + l15];
        long r0 = rowbase + wave * 16 + lg * 4;
#pragma unroll
        for (int r = 0; r < 4; ++r) {
            ext[(r0 + r) * 64 + nq * 16 + l15] = acc[nq][r] + bias;
        }
    }
}

// ---------------------------------------------------------------------------
// Kernel 3 (v7): readlane scan, TWO BATCHES PER WAVE (independent chains).
// R14 measured 610 cyc/step at ~276 cyc issue floor -> ~330 cyc/step of
// dependency stall in a single serial chain with nothing to fill it (1
// wave/SIMD, Occ 3%).  Two interleaved batch chains share w[64] and fill
// each other's rl->fma / fma->fma hazard slots: per-batch cost drops toward
// the issue floor.  Groups of 16 rl then 16 fma per batch, alternating.
// ---------------------------------------------------------------------------
__device__ inline float rl(float v, int k) {
    return __int_as_float(__builtin_amdgcn_readlane(__float_as_int(v), k));
}

__global__ __launch_bounds__(64) void scan_kernel(const float* __restrict__ ext,
                                                  const float* __restrict__ Wrec,
                                                  const float* __restrict__ brec,
                                                  float* __restrict__ states) {
    const int b0 = blockIdx.x * 2;   // this wave's two batches
    const int h  = threadIdx.x;      // 0..63

    float w[64];
#pragma unroll
    for (int i = 0; i < 16; ++i)
        *(f32x4*)&w[i * 4] = *(const f32x4*)&Wrec[h * 64 + i * 4];
    const float bias = brec[h];

    const float* ep0 = ext + (size_t)b0 * 512 * 64 + h;
    const float* ep1 = ep0 + 512 * 64;
    float* sp0 = states + (size_t)b0 * 512 * 64 + h;
    float* sp1 = sp0 + 512 * 64;

    float s0 = 0.f, s1 = 0.f;
    float ea[4], eb[4];
#pragma unroll
    for (int i = 0; i < 4; ++i) {
        ea[i] = ep0[(size_t)i * 64];
        eb[i] = ep1[(size_t)i * 64];
    }

#define SCAN_STEP(IDX)                                                          \
    {                                                                           \
        float in0 = s0 + ea[IDX];                                               \
        float in1 = s1 + eb[IDX];                                               \
        int tn = t + 4 + (IDX); tn = tn > 511 ? 511 : tn;                       \
        ea[IDX] = ep0[(size_t)tn * 64];                                         \
        eb[IDX] = ep1[(size_t)tn * 64];                                         \
        float a0_[4] = {bias, 0.f, 0.f, 0.f};                                   \
        float a1_[4] = {bias, 0.f, 0.f, 0.f};                                   \
        _Pragma("unroll")                                                       \
        for (int g = 0; g < 4; ++g) {                                           \
            float r0[16], r1[16];                                               \
            _Pragma("unroll")                                                   \
            for (int j = 0; j < 16; ++j) r0[j] = rl(in0, g * 16 + j);           \
            _Pragma("unroll")                                                   \
            for (int j = 0; j < 16; ++j) r1[j] = rl(in1, g * 16 + j);           \
            _Pragma("unroll")                                                   \
            for (int j = 0; j < 16; ++j)                                        \
                a0_[j & 3] = fmaf(w[g * 16 + j], r0[j], a0_[j & 3]);            \
            _Pragma("unroll")                                                   \
            for (int j = 0; j < 16; ++j)                                        \
                a1_[j & 3] = fmaf(w[g * 16 + j], r1[j], a1_[j & 3]);            \
        }                                                                       \
        s0 = fmaxf((a0_[0] + a0_[1]) + (a0_[2] + a0_[3]), 0.f);                 \
        s1 = fmaxf((a1_[0] + a1_[1]) + (a1_[2] + a1_[3]), 0.f);                 \
        sp0[(size_t)(t + (IDX)) * 64] = s0;                                     \
        sp1[(size_t)(t + (IDX)) * 64] = s1;                                     \
    }

#pragma unroll 1
    for (int t = 0; t < 512; t += 4) {
        SCAN_STEP(0)
        SCAN_STEP(1)
        SCAN_STEP(2)
        SCAN_STEP(3)
    }
#undef SCAN_STEP
}

// ---------------------------------------------------------------------------
// Kernel 4: output head.  (byte-identical to R4..R16)
// ---------------------------------------------------------------------------
__global__ __launch_bounds__(256) void head_kernel(const float* __restrict__ states,
                                                   const float* __restrict__ Wo1,
                                                   const float* __restrict__ bo1,
                                                   const float* __restrict__ Wo2,
                                                   const float* __restrict__ bo2,
                                                   float* __restrict__ out) {
    __shared__ float W1t[64][32];   // W1t[k][j] = Wo1[j][k]
    __shared__ float w2s[64];
    __shared__ float b1s[32];
    __shared__ float b2s[2];

    const int tid = threadIdx.x;
    for (int idx = tid; idx < 2048; idx += 256) {
        int j = idx >> 6, k = idx & 63;
        W1t[k][j] = Wo1[idx];
    }
    if (tid < 64) w2s[tid] = Wo2[tid];
    if (tid < 32) b1s[tid] = bo1[tid];
    if (tid < 2)  b2s[tid] = bo2[tid];
    __syncthreads();

    const size_t row = (size_t)blockIdx.x * 256 + tid;  // 0..131071
    const float* srow = states + row * 64;

    float st[64];
#pragma unroll
    for (int i = 0; i < 16; ++i)
        *(float4*)&st[i * 4] = *(const float4*)&srow[i * 4];

    float4 hacc[8];
#pragma unroll
    for (int j4 = 0; j4 < 8; ++j4) hacc[j4] = (float4){0.f, 0.f, 0.f, 0.f};

#pragma unroll
    for (int k = 0; k < 64; ++k) {
        float sk = st[k];
#pragma unroll
        for (int j4 = 0; j4 < 8; ++j4) {
            float4 wv = *(const float4*)&W1t[k][j4 * 4];
            hacc[j4].x += sk * wv.x;
            hacc[j4].y += sk * wv.y;
            hacc[j4].z += sk * wv.z;
            hacc[j4].w += sk * wv.w;
        }
    }

    float o0 = b2s[0], o1 = b2s[1];
#pragma unroll
    for (int j4 = 0; j4 < 8; ++j4) {
        float4 bv = *(const float4*)&b1s[j4 * 4];
        float hj[4] = {fmaxf(hacc[j4].x + bv.x, 0.f), fmaxf(hacc[j4].y + bv.y, 0.f),
                       fmaxf(hacc[j4].z + bv.z, 0.f), fmaxf(hacc[j4].w + bv.w, 0.f)};
#pragma unroll
        for (int r = 0; r < 4; ++r) {
            int j = j4 * 4 + r;
            o0 += hj[r] * w2s[j];
            o1 += hj[r] * w2s[32 + j];
        }
    }
    float2 ov = {o0, o1};
    *(float2*)&out[row * 2] = ov;
}

// ---------------------------------------------------------------------------
extern "C" void kernel_launch(void* const* d_in, const int* in_sizes, int n_in,
                              void* d_out, int out_size, void* d_ws, size_t ws_size,
                              hipStream_t stream) {
    (void)in_sizes; (void)n_in; (void)out_size; (void)ws_size;

    const float* x     = (const float*)d_in[0];
    const float* W_in  = (const float*)d_in[1];
    const float* b_in  = (const float*)d_in[2];
    const float* W_rec = (const float*)d_in[3];
    const float* b_rec = (const float*)d_in[4];
    const float* W_o1  = (const float*)d_in[5];
    const float* b_o1  = (const float*)d_in[6];
    const float* W_o2  = (const float*)d_in[7];
    const float* b_o2  = (const float*)d_in[8];
    float* out = (float*)d_out;

    char* ws = (char*)d_ws;
    ushort_t* Wp   = (ushort_t*)ws;                                  // 256 KB
    float* ext     = (float*)(ws + (1u << 20));                      // 32 MB
    float* states  = (float*)(ws + (1u << 20) + (32u << 20));        // 32 MB

    pack_w_kernel<<<256, 256, 0, stream>>>(W_in, Wp);
    gemm_ext_kernel<<<2048, 256, 0, stream>>>(x, Wp, b_in, ext);
    scan_kernel<<<128, 64, 0, stream>>>(ext, W_rec, b_rec, states);
    head_kernel<<<512, 256, 0, stream>>>(states, W_o1, b_o1, W_o2, b_o2, out);
}

// Round 18
// 303.260 us; speedup vs baseline: 1.3899x; 1.3899x over previous
//
#include <hip/hip_runtime.h>

typedef __attribute__((ext_vector_type(8))) short bf16x8;
typedef __attribute__((ext_vector_type(4))) float f32x4;
typedef unsigned short ushort_t;

// ---------------------------------------------------------------------------
// fp32 -> bf16 RNE helpers
// ---------------------------------------------------------------------------
__device__ inline unsigned f2bf_rnd(float f) {
    unsigned u = __float_as_uint(f);
    return u + 0x7FFFu + ((u >> 16) & 1u);   // high 16 bits = RNE bf16
}

__device__ inline void split8(f32x4 a, f32x4 b, bf16x8& hv, bf16x8& lv) {
    float f[8] = {a.x, a.y, a.z, a.w, b.x, b.y, b.z, b.w};
    unsigned r[8], l[8];
#pragma unroll
    for (int j = 0; j < 8; ++j) r[j] = f2bf_rnd(f[j]);
#pragma unroll
    for (int j = 0; j < 8; ++j) {
        float hf = __uint_as_float(r[j] & 0xFFFF0000u);
        l[j] = f2bf_rnd(f[j] - hf);
    }
    union { unsigned u[4]; bf16x8 v; } H, L;
#pragma unroll
    for (int p = 0; p < 4; ++p) {
        H.u[p] = __builtin_amdgcn_perm(r[2 * p + 1], r[2 * p], 0x07060302u);
        L.u[p] = __builtin_amdgcn_perm(l[2 * p + 1], l[2 * p], 0x07060302u);
    }
    hv = H.v; lv = L.v;
}

// direct HBM->LDS DMA, 16B per lane; LDS dest = wave-uniform base + lane*16
__device__ inline void gload_lds16(const void* g, void* l) {
    __builtin_amdgcn_global_load_lds(
        (const __attribute__((address_space(1))) void*)g,
        (__attribute__((address_space(3))) void*)l, 16, 0, 0);
}

// ---------------------------------------------------------------------------
// Kernel 1: pack W_in [64][1024] fp32 -> Wp bf16 hi/lo in MFMA-fragment layout
// Wp layout: [chunk 32][hl 2][kg 4][n 64][j 8]  (ushort), 256 KB total
// (byte-identical to R12..R17)
// ---------------------------------------------------------------------------
__global__ void pack_w_kernel(const float* __restrict__ Win, ushort_t* __restrict__ Wp) {
    int idx = blockIdx.x * 256 + threadIdx.x;   // 0..65535
    int j  = idx & 7;
    int n  = (idx >> 3) & 63;
    int kg = (idx >> 9) & 3;
    int ch = idx >> 11;                          // 0..31
    int k  = ch * 32 + kg * 8 + j;
    float v = Win[n * 1024 + k];
    unsigned hb = f2bf_rnd(v) >> 16;
    float hf = __uint_as_float(hb << 16);
    unsigned lb = f2bf_rnd(v - hf) >> 16;
    Wp[((ch * 2 + 0) * 4 + kg) * 512 + n * 8 + j] = (ushort_t)hb;
    Wp[((ch * 2 + 1) * 4 + kg) * 512 + n * 8 + j] = (ushort_t)lb;
}

// ---------------------------------------------------------------------------
// Kernel 2 (v7): ext = x @ W_in^T + b_in, bf16 MFMA 3-term split.
// BM=64, BK=32, 256 thr (4 waves x 16 rows).  4-BUFFER global_load_lds
// pipeline (64 KB static LDS), SINGLE barrier per tile, issue BEFORE compute:
//   vmcnt(8)        <- tile kt landed; kt+1,kt+2 still in flight
//   s_barrier       <- kt visible; compute(kt-1)'s reads of buf (kt+3)&3 done
//   issue kt+3      <- 3 tiles now in flight THROUGH the compute phase
//   compute(kt)
// HBM never drains (v4b's 2-deep pipeline idled HBM each tile: 900cyc
// latency > 450cyc compute).  Tail: vmcnt(4)@30, vmcnt(0)@31.
// ---------------------------------------------------------------------------
__global__ __launch_bounds__(256) void gemm_ext_kernel(const float* __restrict__ x,
                                                       const ushort_t* __restrict__ Wp,
                                                       const float* __restrict__ bin,
                                                       float* __restrict__ ext) {
    __shared__ __align__(16) float    Asm[4][2048];   // 4 x 8 KB  [row][col32]
    __shared__ __align__(16) ushort_t Bsm[4][4096];   // 4 x 8 KB

    const int tid  = threadIdx.x;        // 0..255
    const int lane = tid & 63;
    const int wave = tid >> 6;
    const int l15  = lane & 15;
    const int lg   = lane >> 4;

    const long rowbase = (long)blockIdx.x * 64;

    auto issue_tile = [&](int kt, int buf) {
        const float* xb = x + rowbase * 1024 + kt * 32;
        const ushort_t* wb = Wp + kt * 4096;
#pragma unroll
        for (int i = 0; i < 2; ++i) {
            const int slot = i * 256 + tid;           // row = slot>>3, seg = slot&7
            gload_lds16(xb + (long)(slot >> 3) * 1024 + (slot & 7) * 4,
                        &Asm[buf][(i * 256 + wave * 64) * 4]);
        }
#pragma unroll
        for (int i = 0; i < 2; ++i) {
            const int slot = i * 256 + tid;
            gload_lds16(wb + slot * 8,
                        &Bsm[buf][(i * 256 + wave * 64) * 8]);
        }
    };

    f32x4 acc[4];
#pragma unroll
    for (int n = 0; n < 4; ++n) acc[n] = (f32x4){0.f, 0.f, 0.f, 0.f};

    issue_tile(0, 0);
    issue_tile(1, 1);
    issue_tile(2, 2);

#pragma unroll 1
    for (int kt = 0; kt < 32; ++kt) {
        const int buf = kt & 3;
        if (kt <= 29) {
            asm volatile("s_waitcnt vmcnt(8)" ::: "memory");
        } else if (kt == 30) {
            asm volatile("s_waitcnt vmcnt(4)" ::: "memory");
        } else {
            asm volatile("s_waitcnt vmcnt(0)" ::: "memory");
        }
        asm volatile("s_barrier" ::: "memory");

        if (kt + 3 < 32) issue_tile(kt + 3, (kt + 3) & 3);

        const float* ap = &Asm[buf][(wave * 16 + l15) * 32 + lg * 8];
        f32x4 a0 = *(const f32x4*)ap;
        f32x4 a1 = *(const f32x4*)(ap + 4);
        bf16x8 Ahi, Alo;
        split8(a0, a1, Ahi, Alo);
        const ushort_t* bp = &Bsm[buf][lg * 512 + l15 * 8];
#pragma unroll
        for (int nq = 0; nq < 4; ++nq) {
            bf16x8 bh = *(const bf16x8*)(bp + nq * 128);
            bf16x8 bl = *(const bf16x8*)(bp + 2048 + nq * 128);
            acc[nq] = __builtin_amdgcn_mfma_f32_16x16x32_bf16(Ahi, bh, acc[nq], 0, 0, 0);
            acc[nq] = __builtin_amdgcn_mfma_f32_16x16x32_bf16(Ahi, bl, acc[nq], 0, 0, 0);
            acc[nq] = __builtin_amdgcn_mfma_f32_16x16x32_bf16(Alo, bh, acc[nq], 0, 0, 0);
        }
    }

    // epilogue: add bias, store.  C/D map: col = lane&15, row = (lane>>4)*4 + r
#pragma unroll
    for (int nq = 0; nq < 4; ++nq) {
        float bias = bin[nq * 16 + l15];
        long r0 = rowbase + wave * 16 + lg * 4;
#pragma unroll
        for (int r = 0; r < 4; ++r) {
            ext[(r0 + r) * 64 + nq * 16 + l15] = acc[nq][r] + bias;
        }
    }
}

// ---------------------------------------------------------------------------
// Kernel 3 (v4, byte-identical to R14's measured-130us scan): readlane with
// sched_barrier(0)-pinned groups, one batch per wave, grid 256.
// R17 falsified the ILP theory (two chains = 2x time): the wave is
// throughput-bound on the VALU port (~8 cyc per v_readlane) -- this is the
// structure's floor.
// ---------------------------------------------------------------------------
__device__ inline float rl(float v, int k) {
    return __int_as_float(__builtin_amdgcn_readlane(__float_as_int(v), k));
}

__global__ __launch_bounds__(64) void scan_kernel(const float* __restrict__ ext,
                                                  const float* __restrict__ Wrec,
                                                  const float* __restrict__ brec,
                                                  float* __restrict__ states) {
    const int b = blockIdx.x;
    const int h = threadIdx.x;   // 0..63

    float w[64];
#pragma unroll
    for (int i = 0; i < 16; ++i)
        *(f32x4*)&w[i * 4] = *(const f32x4*)&Wrec[h * 64 + i * 4];
    const float bias = brec[h];

    const float* ep = ext + (size_t)b * 512 * 64 + h;
    float* sp = states + (size_t)b * 512 * 64 + h;

    float s = 0.f;
    float e0 = ep[0];
    float e1 = ep[64];
    float e2 = ep[128];
    float e3 = ep[192];

#define RLG(DST, BASE)                                                          \
    _Pragma("unroll")                                                           \
    for (int j = 0; j < 16; ++j) DST[j] = rl(in, (BASE) + j);                   \
    __builtin_amdgcn_sched_barrier(0);

#define FMAG(SRC, BASE)                                                         \
    _Pragma("unroll")                                                           \
    for (int j = 0; j < 16; ++j)                                                \
        a[j & 3] = fmaf(w[(BASE) + j], SRC[j], a[j & 3]);                       \
    __builtin_amdgcn_sched_barrier(0);

#define SCAN_STEP(EREG, IDX)                                                    \
    {                                                                           \
        float in = s + EREG;                                                    \
        int tn = t + 4 + (IDX); tn = tn > 511 ? 511 : tn;                       \
        EREG = ep[(size_t)tn * 64];                                             \
        float ra[16], rb[16];                                                   \
        float a[4] = {bias, 0.f, 0.f, 0.f};                                     \
        RLG(ra, 0)                                                              \
        RLG(rb, 16)                                                             \
        FMAG(ra, 0)                                                             \
        RLG(ra, 32)                                                             \
        FMAG(rb, 16)                                                            \
        RLG(rb, 48)                                                             \
        FMAG(ra, 32)                                                            \
        FMAG(rb, 48)                                                            \
        s = fmaxf((a[0] + a[1]) + (a[2] + a[3]), 0.f);                          \
        sp[(size_t)(t + (IDX)) * 64] = s;                                       \
    }

#pragma unroll 1
    for (int t = 0; t < 512; t += 4) {
        SCAN_STEP(e0, 0)
        SCAN_STEP(e1, 1)
        SCAN_STEP(e2, 2)
        SCAN_STEP(e3, 3)
    }
#undef SCAN_STEP
#undef RLG
#undef FMAG
}

// ---------------------------------------------------------------------------
// Kernel 4: output head.  (byte-identical to R4..R17)
// ---------------------------------------------------------------------------
__global__ __launch_bounds__(256) void head_kernel(const float* __restrict__ states,
                                                   const float* __restrict__ Wo1,
                                                   const float* __restrict__ bo1,
                                                   const float* __restrict__ Wo2,
                                                   const float* __restrict__ bo2,
                                                   float* __restrict__ out) {
    __shared__ float W1t[64][32];   // W1t[k][j] = Wo1[j][k]
    __shared__ float w2s[64];
    __shared__ float b1s[32];
    __shared__ float b2s[2];

    const int tid = threadIdx.x;
    for (int idx = tid; idx < 2048; idx += 256) {
        int j = idx >> 6, k = idx & 63;
        W1t[k][j] = Wo1[idx];
    }
    if (tid < 64) w2s[tid] = Wo2[tid];
    if (tid < 32) b1s[tid] = bo1[tid];
    if (tid < 2)  b2s[tid] = bo2[tid];
    __syncthreads();

    const size_t row = (size_t)blockIdx.x * 256 + tid;  // 0..131071
    const float* srow = states + row * 64;

    float st[64];
#pragma unroll
    for (int i = 0; i < 16; ++i)
        *(float4*)&st[i * 4] = *(const float4*)&srow[i * 4];

    float4 hacc[8];
#pragma unroll
    for (int j4 = 0; j4 < 8; ++j4) hacc[j4] = (float4){0.f, 0.f, 0.f, 0.f};

#pragma unroll
    for (int k = 0; k < 64; ++k) {
        float sk = st[k];
#pragma unroll
        for (int j4 = 0; j4 < 8; ++j4) {
            float4 wv = *(const float4*)&W1t[k][j4 * 4];
            hacc[j4].x += sk * wv.x;
            hacc[j4].y += sk * wv.y;
            hacc[j4].z += sk * wv.z;
            hacc[j4].w += sk * wv.w;
        }
    }

    float o0 = b2s[0], o1 = b2s[1];
#pragma unroll
    for (int j4 = 0; j4 < 8; ++j4) {
        float4 bv = *(const float4*)&b1s[j4 * 4];
        float hj[4] = {fmaxf(hacc[j4].x + bv.x, 0.f), fmaxf(hacc[j4].y + bv.y, 0.f),
                       fmaxf(hacc[j4].z + bv.z, 0.f), fmaxf(hacc[j4].w + bv.w, 0.f)};
#pragma unroll
        for (int r = 0; r < 4; ++r) {
            int j = j4 * 4 + r;
            o0 += hj[r] * w2s[j];
            o1 += hj[r] * w2s[32 + j];
        }
    }
    float2 ov = {o0, o1};
    *(float2*)&out[row * 2] = ov;
}

// ---------------------------------------------------------------------------
extern "C" void kernel_launch(void* const* d_in, const int* in_sizes, int n_in,
                              void* d_out, int out_size, void* d_ws, size_t ws_size,
                              hipStream_t stream) {
    (void)in_sizes; (void)n_in; (void)out_size; (void)ws_size;

    const float* x     = (const float*)d_in[0];
    const float* W_in  = (const float*)d_in[1];
    const float* b_in  = (const float*)d_in[2];
    const float* W_rec = (const float*)d_in[3];
    const float* b_rec = (const float*)d_in[4];
    const float* W_o1  = (const float*)d_in[5];
    const float* b_o1  = (const float*)d_in[6];
    const float* W_o2  = (const float*)d_in[7];
    const float* b_o2  = (const float*)d_in[8];
    float* out = (float*)d_out;

    char* ws = (char*)d_ws;
    ushort_t* Wp   = (ushort_t*)ws;                                  // 256 KB
    float* ext     = (float*)(ws + (1u << 20));                      // 32 MB
    float* states  = (float*)(ws + (1u << 20) + (32u << 20));        // 32 MB

    pack_w_kernel<<<256, 256, 0, stream>>>(W_in, Wp);
    gemm_ext_kernel<<<2048, 256, 0, stream>>>(x, Wp, b_in, ext);
    scan_kernel<<<256, 64, 0, stream>>>(ext, W_rec, b_rec, states);
    head_kernel<<<512, 256, 0, stream>>>(states, W_o1, b_o1, W_o2, b_o2, out);
}

// Round 20
// 251.256 us; speedup vs baseline: 1.6776x; 1.2070x over previous
//
#include <hip/hip_runtime.h>

typedef __attribute__((ext_vector_type(8))) short bf16x8;
typedef __attribute__((ext_vector_type(4))) float f32x4;
typedef __fp16 h16x2 __attribute__((ext_vector_type(2)));
typedef unsigned short ushort_t;

// ---------------------------------------------------------------------------
// fp32 -> bf16 RNE helpers
// ---------------------------------------------------------------------------
__device__ inline unsigned f2bf_rnd(float f) {
    unsigned u = __float_as_uint(f);
    return u + 0x7FFFu + ((u >> 16) & 1u);   // high 16 bits = RNE bf16
}

__device__ inline void split8(f32x4 a, f32x4 b, bf16x8& hv, bf16x8& lv) {
    float f[8] = {a.x, a.y, a.z, a.w, b.x, b.y, b.z, b.w};
    unsigned r[8], l[8];
#pragma unroll
    for (int j = 0; j < 8; ++j) r[j] = f2bf_rnd(f[j]);
#pragma unroll
    for (int j = 0; j < 8; ++j) {
        float hf = __uint_as_float(r[j] & 0xFFFF0000u);
        l[j] = f2bf_rnd(f[j] - hf);
    }
    union { unsigned u[4]; bf16x8 v; } H, L;
#pragma unroll
    for (int p = 0; p < 4; ++p) {
        H.u[p] = __builtin_amdgcn_perm(r[2 * p + 1], r[2 * p], 0x07060302u);
        L.u[p] = __builtin_amdgcn_perm(l[2 * p + 1], l[2 * p], 0x07060302u);
    }
    hv = H.v; lv = L.v;
}

// direct HBM->LDS DMA, 16B per lane; LDS dest = wave-uniform base + lane*16
__device__ inline void gload_lds16(const void* g, void* l) {
    __builtin_amdgcn_global_load_lds(
        (const __attribute__((address_space(1))) void*)g,
        (__attribute__((address_space(3))) void*)l, 16, 0, 0);
}

// ---------------------------------------------------------------------------
// Kernel 1: pack W_in [64][1024] fp32 -> Wp bf16 hi/lo in MFMA-fragment layout
// Wp layout: [chunk 32][hl 2][kg 4][n 64][j 8]  (ushort), 256 KB total
// (byte-identical to R12..R19)
// ---------------------------------------------------------------------------
__global__ void pack_w_kernel(const float* __restrict__ Win, ushort_t* __restrict__ Wp) {
    int idx = blockIdx.x * 256 + threadIdx.x;   // 0..65535
    int j  = idx & 7;
    int n  = (idx >> 3) & 63;
    int kg = (idx >> 9) & 3;
    int ch = idx >> 11;                          // 0..31
    int k  = ch * 32 + kg * 8 + j;
    float v = Win[n * 1024 + k];
    unsigned hb = f2bf_rnd(v) >> 16;
    float hf = __uint_as_float(hb << 16);
    unsigned lb = f2bf_rnd(v - hf) >> 16;
    Wp[((ch * 2 + 0) * 4 + kg) * 512 + n * 8 + j] = (ushort_t)hb;
    Wp[((ch * 2 + 1) * 4 + kg) * 512 + n * 8 + j] = (ushort_t)lb;
}

// ---------------------------------------------------------------------------
// Kernel 2 (v4b, byte-identical to R14's measured-131us GEMM): global_load_lds
// pipeline, counted vmcnt, two barriers/tile, compiler-interleaved ds_reads.
// ---------------------------------------------------------------------------
__global__ __launch_bounds__(256) void gemm_ext_kernel(const float* __restrict__ x,
                                                       const ushort_t* __restrict__ Wp,
                                                       const float* __restrict__ bin,
                                                       float* __restrict__ ext) {
    __shared__ __align__(16) float    Asm[2][4096];   // 2 x 16 KB, [row][col64]
    __shared__ __align__(16) ushort_t Bsm[2][8192];   // 2 x 16 KB, linear

    const int tid  = threadIdx.x;        // 0..255
    const int lane = tid & 63;
    const int wave = tid >> 6;
    const int l15  = lane & 15;
    const int lg   = lane >> 4;

    const long rowbase = (long)blockIdx.x * 64;

    auto issue_tile = [&](int kt, int buf) {
        const float* xb = x + rowbase * 1024 + kt * 64;
        const ushort_t* wb = Wp + kt * 8192;
#pragma unroll
        for (int i = 0; i < 4; ++i) {
            const int slot = i * 256 + tid;           // = i*256 + wave*64 + lane
            gload_lds16(xb + (long)(slot >> 4) * 1024 + (slot & 15) * 4,
                        &Asm[buf][(i * 256 + wave * 64) * 4]);
        }
#pragma unroll
        for (int i = 0; i < 4; ++i) {
            const int slot = i * 256 + tid;
            gload_lds16(wb + slot * 8,
                        &Bsm[buf][(i * 256 + wave * 64) * 8]);
        }
    };

    f32x4 acc[4];
#pragma unroll
    for (int n = 0; n < 4; ++n) acc[n] = (f32x4){0.f, 0.f, 0.f, 0.f};

    issue_tile(0, 0);
    issue_tile(1, 1);

#pragma unroll 1
    for (int kt = 0; kt < 16; ++kt) {
        const int buf = kt & 1;
        if (kt < 15) {
            asm volatile("s_waitcnt vmcnt(8)" ::: "memory");
        } else {
            asm volatile("s_waitcnt vmcnt(0)" ::: "memory");
        }
        asm volatile("s_barrier" ::: "memory");

#pragma unroll
        for (int kc = 0; kc < 2; ++kc) {
            const float* ap = &Asm[buf][(wave * 16 + l15) * 64 + kc * 32 + lg * 8];
            f32x4 a0 = *(const f32x4*)ap;
            f32x4 a1 = *(const f32x4*)(ap + 4);
            bf16x8 Ahi, Alo;
            split8(a0, a1, Ahi, Alo);
            const ushort_t* bp = &Bsm[buf][kc * 4096 + lg * 512 + l15 * 8];
#pragma unroll
            for (int nq = 0; nq < 4; ++nq) {
                bf16x8 bh = *(const bf16x8*)(bp + nq * 128);
                bf16x8 bl = *(const bf16x8*)(bp + 2048 + nq * 128);
                acc[nq] = __builtin_amdgcn_mfma_f32_16x16x32_bf16(Ahi, bh, acc[nq], 0, 0, 0);
                acc[nq] = __builtin_amdgcn_mfma_f32_16x16x32_bf16(Ahi, bl, acc[nq], 0, 0, 0);
                acc[nq] = __builtin_amdgcn_mfma_f32_16x16x32_bf16(Alo, bh, acc[nq], 0, 0, 0);
            }
        }

        if (kt + 2 < 16) {
            asm volatile("s_barrier" ::: "memory");   // all waves done reading buf
            issue_tile(kt + 2, buf);
        }
    }

    // epilogue: add bias, store.  C/D map: col = lane&15, row = (lane>>4)*4 + r
#pragma unroll
    for (int nq = 0; nq < 4; ++nq) {
        float bias = bin[nq * 16 + l15];
        long r0 = rowbase + wave * 16 + lg * 4;
#pragma unroll
        for (int r = 0; r < 4; ++r) {
            ext[(r0 + r) * 64 + nq * 16 + l15] = acc[nq][r] + bias;
        }
    }
}

// ---------------------------------------------------------------------------
// Kernel 3 (v8): scan with PAIRED-f16 broadcast + v_dot2_f32_f16.
// R17 proved readlane-THROUGHPUT-bound (~8cyc/readlane, 64/step = 512 of the
// 610 cyc).  Halve the readlanes: pack (in[2j],in[2j+1]) as half2 in even
// lanes (mov_dpp quad_perm neighbor swap + cvt_pkrtz), 32 readlanes of
// packed pairs, 32 v_dot2_f32_f16 (fp32 accumulate) replace 64 fma.
// W row pre-packed to 32 half2.  Predicted ~350 cyc/step vs 610.
// ---------------------------------------------------------------------------
__device__ inline h16x2 i2h(int x) { union { int i; h16x2 h; } u; u.i = x; return u.h; }

__global__ __launch_bounds__(64) void scan_kernel(const float* __restrict__ ext,
                                                  const float* __restrict__ Wrec,
                                                  const float* __restrict__ brec,
                                                  float* __restrict__ states) {
    const int b = blockIdx.x;
    const int h = threadIdx.x;   // 0..63

    float wtmp[64];
#pragma unroll
    for (int i = 0; i < 16; ++i)
        *(f32x4*)&wtmp[i * 4] = *(const f32x4*)&Wrec[h * 64 + i * 4];
    h16x2 wp[32];
#pragma unroll
    for (int j = 0; j < 32; ++j)
        wp[j] = __builtin_amdgcn_cvt_pkrtz(wtmp[2 * j], wtmp[2 * j + 1]);
    const float bias = brec[h];

    const float* ep = ext + (size_t)b * 512 * 64 + h;
    float* sp = states + (size_t)b * 512 * 64 + h;

    float s = 0.f;
    float e0 = ep[0];
    float e1 = ep[64];
    float e2 = ep[128];
    float e3 = ep[192];

#define RLG(DST, BASE)                                                          \
    _Pragma("unroll")                                                           \
    for (int j = 0; j < 8; ++j) DST[j] = __builtin_amdgcn_readlane(h2i, 2 * ((BASE) + j)); \
    __builtin_amdgcn_sched_barrier(0);

#define DOTG(SRC, BASE)                                                         \
    _Pragma("unroll")                                                           \
    for (int j = 0; j < 8; ++j)                                                 \
        a[j & 3] = __builtin_amdgcn_fdot2(wp[(BASE) + j], i2h(SRC[j]), a[j & 3], false); \
    __builtin_amdgcn_sched_barrier(0);

#define SCAN_STEP(EREG, IDX)                                                    \
    {                                                                           \
        float in = s + EREG;                                                    \
        int tn = t + 4 + (IDX); tn = tn > 511 ? 511 : tn;                       \
        EREG = ep[(size_t)tn * 64];                                             \
        int ivi = __float_as_int(in);                                           \
        int nbi = __builtin_amdgcn_mov_dpp(ivi, 0xB1, 0xF, 0xF, true);          \
        h16x2 h2 = __builtin_amdgcn_cvt_pkrtz(in, __int_as_float(nbi));         \
        int h2i; { union { h16x2 h; int i; } u; u.h = h2; h2i = u.i; }          \
        int ra[8], rb[8];                                                       \
        float a[4] = {bias, 0.f, 0.f, 0.f};                                     \
        RLG(ra, 0)                                                              \
        RLG(rb, 8)                                                              \
        DOTG(ra, 0)                                                             \
        RLG(ra, 16)                                                             \
        DOTG(rb, 8)                                                             \
        RLG(rb, 24)                                                             \
        DOTG(ra, 16)                                                            \
        DOTG(rb, 24)                                                            \
        s = fmaxf((a[0] + a[1]) + (a[2] + a[3]), 0.f);                          \
        sp[(size_t)(t + (IDX)) * 64] = s;                                       \
    }

#pragma unroll 1
    for (int t = 0; t < 512; t += 4) {
        SCAN_STEP(e0, 0)
        SCAN_STEP(e1, 1)
        SCAN_STEP(e2, 2)
        SCAN_STEP(e3, 3)
    }
#undef SCAN_STEP
#undef RLG
#undef DOTG
}

// ---------------------------------------------------------------------------
// Kernel 4: output head.  (byte-identical to R4..R19)
// ---------------------------------------------------------------------------
__global__ __launch_bounds__(256) void head_kernel(const float* __restrict__ states,
                                                   const float* __restrict__ Wo1,
                                                   const float* __restrict__ bo1,
                                                   const float* __restrict__ Wo2,
                                                   const float* __restrict__ bo2,
                                                   float* __restrict__ out) {
    __shared__ float W1t[64][32];   // W1t[k][j] = Wo1[j][k]
    __shared__ float w2s[64];
    __shared__ float b1s[32];
    __shared__ float b2s[2];

    const int tid = threadIdx.x;
    for (int idx = tid; idx < 2048; idx += 256) {
        int j = idx >> 6, k = idx & 63;
        W1t[k][j] = Wo1[idx];
    }
    if (tid < 64) w2s[tid] = Wo2[tid];
    if (tid < 32) b1s[tid] = bo1[tid];
    if (tid < 2)  b2s[tid] = bo2[tid];
    __syncthreads();

    const size_t row = (size_t)blockIdx.x * 256 + tid;  // 0..131071
    const float* srow = states + row * 64;

    float st[64];
#pragma unroll
    for (int i = 0; i < 16; ++i)
        *(float4*)&st[i * 4] = *(const float4*)&srow[i * 4];

    float4 hacc[8];
#pragma unroll
    for (int j4 = 0; j4 < 8; ++j4) hacc[j4] = (float4){0.f, 0.f, 0.f, 0.f};

#pragma unroll
    for (int k = 0; k < 64; ++k) {
        float sk = st[k];
#pragma unroll
        for (int j4 = 0; j4 < 8; ++j4) {
            float4 wv = *(const float4*)&W1t[k][j4 * 4];
            hacc[j4].x += sk * wv.x;
            hacc[j4].y += sk * wv.y;
            hacc[j4].z += sk * wv.z;
            hacc[j4].w += sk * wv.w;
        }
    }

    float o0 = b2s[0], o1 = b2s[1];
#pragma unroll
    for (int j4 = 0; j4 < 8; ++j4) {
        float4 bv = *(const float4*)&b1s[j4 * 4];
        float hj[4] = {fmaxf(hacc[j4].x + bv.x, 0.f), fmaxf(hacc[j4].y + bv.y, 0.f),
                       fmaxf(hacc[j4].z + bv.z, 0.f), fmaxf(hacc[j4].w + bv.w, 0.f)};
#pragma unroll
        for (int r = 0; r < 4; ++r) {
            int j = j4 * 4 + r;
            o0 += hj[r] * w2s[j];
            o1 += hj[r] * w2s[32 + j];
        }
    }
    float2 ov = {o0, o1};
    *(float2*)&out[row * 2] = ov;
}

// ---------------------------------------------------------------------------
extern "C" void kernel_launch(void* const* d_in, const int* in_sizes, int n_in,
                              void* d_out, int out_size, void* d_ws, size_t ws_size,
                              hipStream_t stream) {
    (void)in_sizes; (void)n_in; (void)out_size; (void)ws_size;

    const float* x     = (const float*)d_in[0];
    const float* W_in  = (const float*)d_in[1];
    const float* b_in  = (const float*)d_in[2];
    const float* W_rec = (const float*)d_in[3];
    const float* b_rec = (const float*)d_in[4];
    const float* W_o1  = (const float*)d_in[5];
    const float* b_o1  = (const float*)d_in[6];
    const float* W_o2  = (const float*)d_in[7];
    const float* b_o2  = (const float*)d_in[8];
    float* out = (float*)d_out;

    char* ws = (char*)d_ws;
    ushort_t* Wp   = (ushort_t*)ws;                                  // 256 KB
    float* ext     = (float*)(ws + (1u << 20));                      // 32 MB
    float* states  = (float*)(ws + (1u << 20) + (32u << 20));        // 32 MB

    pack_w_kernel<<<256, 256, 0, stream>>>(W_in, Wp);
    gemm_ext_kernel<<<2048, 256, 0, stream>>>(x, Wp, b_in, ext);
    scan_kernel<<<256, 64, 0, stream>>>(ext, W_rec, b_rec, states);
    head_kernel<<<512, 256, 0, stream>>>(states, W_o1, b_o1, W_o2, b_o2, out);
}